// Round 12
// baseline (183.174 us; speedup 1.0000x reference)
//
#include <hip/hip_runtime.h>
#include <hip/hip_fp16.h>
#include <math.h>

#define NN 8192
#define CH 256
#define NDIST 2080

// ---- ordering/affine-invariant scaling so all f16 split residuals are normal-range ----
// dist operands: p * 2^15 (pure positive scaling -> distance ORDER unchanged; sq * 2^30)
// gemm operands: x,h,agg * 2^4 ; weights * 2^6 ; epilogue un-scales acc by 2^-10
#define PSCL      32768.0f
#define SQSCL     1073741824.0f     // (2^15)^2
#define XSCL      16.0f
#define WSCL      64.0f
#define HSCL      16.0f
#define ACC_UNSCL 0.0009765625f     // 2^-10

typedef unsigned long long u64;
typedef unsigned u32;
typedef __attribute__((ext_vector_type(8))) short s16x8;
typedef __attribute__((ext_vector_type(8))) _Float16 f16x8;
typedef __attribute__((ext_vector_type(4))) float f32x4;

__device__ __forceinline__ f32x4 mfma_h(s16x8 a, s16x8 b, f32x4 c) {
    return __builtin_amdgcn_mfma_f32_16x16x32_f16(
        __builtin_bit_cast(f16x8, a), __builtin_bit_cast(f16x8, b), c, 0, 0, 0);
}

__device__ __forceinline__ u64 umin64(u64 a, u64 b) { return a < b ? a : b; }
__device__ __forceinline__ u64 umax64(u64 a, u64 b) { return a < b ? b : a; }

__device__ __forceinline__ void merge3(u64 &a0, u64 &a1, u64 &a2, u64 b0, u64 b1, u64 b2) {
    u64 m0 = umin64(a0, b0), M0 = umax64(a0, b0);
    u64 m1 = umin64(a1, b1);
    u64 m2 = umin64(a2, b2);
    u64 s  = umin64(M0, m1), S = umax64(M0, m1);
    a0 = m0;
    a1 = s;
    a2 = umin64(S, m2);
}

// ---- 32-bit packed (truncated-dist-key | 7-bit local index) top-3 primitives ----
// key = (ieee_bits(max(d,0)) & 0xFFFFFF80) | local_idx. d>=0 -> bits monotone unsigned.
__device__ __forceinline__ u32 umin32(u32 a, u32 b) { return a < b ? a : b; }
__device__ __forceinline__ u32 umax32(u32 a, u32 b) { return a < b ? b : a; }

__device__ __forceinline__ void ins3u(u32 &t0, u32 &t1, u32 &t2, u32 v) {
    u32 lo0 = umin32(t0, v), hi0 = umax32(t0, v);
    t0 = lo0;
    u32 lo1 = umin32(t1, hi0), hi1 = umax32(t1, hi0);
    t1 = lo1;
    t2 = umin32(t2, hi1);
}

__device__ __forceinline__ void merge3u(u32 &a0, u32 &a1, u32 &a2, u32 b0, u32 b1, u32 b2) {
    u32 m0 = umin32(a0, b0), M0 = umax32(a0, b0);
    u32 m1 = umin32(a1, b1);
    u32 m2 = umin32(a2, b2);
    u32 s  = umin32(M0, m1), S = umax32(M0, m1);
    a0 = m0;
    a1 = s;
    a2 = umin32(S, m2);
}

__device__ __forceinline__ u32 packdi32(float d, u32 lidx) {
    return (__float_as_uint(fmaxf(d, 0.0f)) & 0xFFFFFF80u) | lidx;
}

__device__ __forceinline__ void gl_lds16(const void* g, void* l) {
    __builtin_amdgcn_global_load_lds(
        (const __attribute__((address_space(1))) unsigned int*)g,
        (__attribute__((address_space(3))) unsigned int*)l, 16, 0, 0);
}

// ---------------- f16 2-way split (H = f16(a), M = f16(a - H)) ----------------
__device__ __forceinline__ void split2h(float a, unsigned short& h, unsigned short& m) {
    __half bh = __float2half(a);
    float r = a - __half2float(bh);
    __half bm = __float2half(r);
    h = __half_as_ushort(bh);
    m = __half_as_ushort(bm);
}

__device__ __forceinline__ float h2f(unsigned short u) {
    return __half2float(__ushort_as_half(u));
}

// ------- fused: softmax + sq + f16-split(p*2^15) + f16-split(x*2^4) + outp zeroing
//         PLUS weight f16 splits (W * 2^6) ---
__global__ __launch_bounds__(256) void softmax_split_kernel(
    const float* __restrict__ x, float* __restrict__ sq,
    unsigned short* __restrict__ pa, unsigned short* __restrict__ pb,
    unsigned short* __restrict__ xh, unsigned short* __restrict__ xm,
    float* __restrict__ outp,
    const float* __restrict__ W1, const float* __restrict__ Wrel, const float* __restrict__ Wroot,
    unsigned short* __restrict__ d0h, unsigned short* __restrict__ d0m,
    unsigned short* __restrict__ d1h, unsigned short* __restrict__ d1m,
    unsigned short* __restrict__ d2h, unsigned short* __restrict__ d2m)
{
    if (blockIdx.x >= NN / 4) {
        int wb = blockIdx.x - NN / 4;      // 0..191
        int which = wb >> 6;
        const float* s = (which == 0) ? W1 : (which == 1) ? Wrel : Wroot;
        unsigned short* dh = (which == 0) ? d0h : (which == 1) ? d1h : d2h;
        unsigned short* dm = (which == 0) ? d0m : (which == 1) ? d1m : d2m;
        int i = (wb & 63) * 1024 + threadIdx.x * 4;
        float4 v = *(const float4*)(s + i);
        ushort4 H, M;
        split2h(v.x * WSCL, H.x, M.x);
        split2h(v.y * WSCL, H.y, M.y);
        split2h(v.z * WSCL, H.z, M.z);
        split2h(v.w * WSCL, H.w, M.w);
        *(ushort4*)(dh + i) = H;
        *(ushort4*)(dm + i) = M;
        return;
    }
    int wave = threadIdx.x >> 6, lane = threadIdx.x & 63;
    int row = blockIdx.x * 4 + wave;
    if (lane == 1) {    // zero the linear2 accumulators for this row (gemm2 is atomic)
        outp[row * 2 + 0] = 0.0f;
        outp[row * 2 + 1] = 0.0f;
    }
    const float4* xr = (const float4*)(x + (size_t)row * CH);
    float4 v = xr[lane];
    int i = row * CH + lane * 4;
    ushort4 XH, XM;
    split2h(v.x * XSCL, XH.x, XM.x);
    split2h(v.y * XSCL, XH.y, XM.y);
    split2h(v.z * XSCL, XH.z, XM.z);
    split2h(v.w * XSCL, XH.w, XM.w);
    *(ushort4*)(xh + i) = XH;
    *(ushort4*)(xm + i) = XM;
    float m = fmaxf(fmaxf(v.x, v.y), fmaxf(v.z, v.w));
    #pragma unroll
    for (int off = 32; off; off >>= 1) m = fmaxf(m, __shfl_xor(m, off, 64));
    // p feeds ONLY neighbor selection (and sq) -> fast exp / single divide are safe
    float e0 = __expf(v.x - m), e1 = __expf(v.y - m), e2 = __expf(v.z - m), e3 = __expf(v.w - m);
    float s = (e0 + e1) + (e2 + e3);
    #pragma unroll
    for (int off = 32; off; off >>= 1) s += __shfl_xor(s, off, 64);
    float rs = 1.0f / s;
    float p0 = e0 * rs, p1 = e1 * rs, p2 = e2 * rs, p3 = e3 * rs;
    float qv = (p0 * p0 + p1 * p1) + (p2 * p2 + p3 * p3);
    #pragma unroll
    for (int off = 32; off; off >>= 1) qv += __shfl_xor(qv, off, 64);
    if (lane == 0) sq[row] = qv * SQSCL;        // scaled to match 2^30-scaled dot
    ushort4 H, M;
    split2h(p0 * PSCL, H.x, M.x);
    split2h(p1 * PSCL, H.y, M.y);
    split2h(p2 * PSCL, H.z, M.z);
    split2h(p3 * PSCL, H.w, M.w);
    *(ushort4*)(pa + i) = H;
    *(ushort4*)(pb + i) = M;
}

// ===== FUSED dispatch: blocks [0,2080) = symmetric dist tiles; [2080, 2592) = gemm_h =====
// dist: 128x128 triangular tile, 4 waves (2x2), f16 2-split, 3 products (HH, HM, MH).
// SINGLE-buffer 32 KB LDS, 2 barriers per K-step (R3/R4: beats dbuf at this grid depth).
// __launch_bounds__(256,4) — DO NOT RAISE: (256,5) forced VGPR 48 < the 64-reg
// accumulator -> scratch spills -> FETCH/WRITE x3, dur x2.4 (R6 post-mortem).
// NO setprio (R5: -83%). NO cooperative mega-fusion (R9 race / R10 harness failure).
// Top-3 epilogue on 32-bit packed keys; part stored as u32x3 (band id encoded by slot).
__global__ __launch_bounds__(256, 4) void dist_gemmh_fused(
    const unsigned short* __restrict__ pa, const unsigned short* __restrict__ pb,
    const float* __restrict__ sq,
    u32* __restrict__ part,
    const unsigned short* __restrict__ Ah, const unsigned short* __restrict__ Am,
    const unsigned short* __restrict__ Wh, const unsigned short* __restrict__ Wm,
    const float* __restrict__ bias,
    unsigned short* __restrict__ oh, unsigned short* __restrict__ om)
{
    __shared__ short sA[2][128 * 32];   // [comp][...] 16 KB
    __shared__ short sB[2][128 * 32];   // 16 KB

    int tid = threadIdx.x;
    int wave = tid >> 6, lane = tid & 63;
    int lc = lane & 15, q = lane >> 4;
    int srow = lane >> 2;
    int skq  = ((lane & 3) ^ ((lane >> 3) & 3)) * 8;   // XOR-swizzled global 16B slot
    int cq   = (q ^ ((lc >> 1) & 3)) * 8;              // swizzled LDS slot for frag reads

    if (blockIdx.x >= NDIST) {
        // ---------------- gemm_h branch ----------------
        int b = blockIdx.x - NDIST;                    // 0..511
        int mbase = (b & 127) * 64, nbase = (b >> 7) * 64;
        short* sAh = &sA[0][0];
        short* sAm = &sA[0][64 * 32];
        short* sBh = &sA[1][0];
        short* sBm = &sA[1][64 * 32];

        f32x4 acc[4];
        #pragma unroll
        for (int nt = 0; nt < 4; ++nt) acc[nt] = (f32x4){0.f, 0.f, 0.f, 0.f};

        int r0 = wave * 16;
        const unsigned short* gsrc[4];
        short* ldst[4];
        gsrc[0] = Ah + (size_t)(mbase + r0 + srow) * CH + skq;  ldst[0] = &sAh[r0 * 32];
        gsrc[1] = Am + (size_t)(mbase + r0 + srow) * CH + skq;  ldst[1] = &sAm[r0 * 32];
        gsrc[2] = Wh + (size_t)(nbase + r0 + srow) * CH + skq;  ldst[2] = &sBh[r0 * 32];
        gsrc[3] = Wm + (size_t)(nbase + r0 + srow) * CH + skq;  ldst[3] = &sBm[r0 * 32];

        for (int kk = 0; kk < CH; kk += 32) {
            #pragma unroll
            for (int t = 0; t < 4; ++t) { gl_lds16(gsrc[t], ldst[t]); gsrc[t] += 32; }
            __syncthreads();
            s16x8 aH, aM, bH[4], bM[4];
            aH = *(const s16x8*)&sAh[(wave * 16 + lc) * 32 + cq];
            aM = *(const s16x8*)&sAm[(wave * 16 + lc) * 32 + cq];
            #pragma unroll
            for (int nt = 0; nt < 4; ++nt) {
                bH[nt] = *(const s16x8*)&sBh[(nt * 16 + lc) * 32 + cq];
                bM[nt] = *(const s16x8*)&sBm[(nt * 16 + lc) * 32 + cq];
            }
            #pragma unroll
            for (int nt = 0; nt < 4; ++nt)
                acc[nt] = mfma_h(aH, bH[nt], acc[nt]);
            #pragma unroll
            for (int nt = 0; nt < 4; ++nt)
                acc[nt] = mfma_h(aH, bM[nt], acc[nt]);
            #pragma unroll
            for (int nt = 0; nt < 4; ++nt)
                acc[nt] = mfma_h(aM, bH[nt], acc[nt]);
            __syncthreads();
        }

        #pragma unroll
        for (int nt = 0; nt < 4; ++nt) {
            float bv = bias[nbase + nt * 16 + lc];
            #pragma unroll
            for (int rg = 0; rg < 4; ++rg) {
                int row = mbase + wave * 16 + q * 4 + rg;
                int col = nbase + nt * 16 + lc;
                float v = fmaxf(fmaf(acc[nt][rg], ACC_UNSCL, bv), 0.0f);
                unsigned short hh_, hm_;
                split2h(v * HSCL, hh_, hm_);
                oh[(size_t)row * CH + col] = hh_;
                om[(size_t)row * CH + col] = hm_;
            }
        }
        return;
    }

    // ---------------- dist branch (XCD-swizzled compact triangular id) ----------------
    u32* rowbuf = (u32*)&sA[0][0];          // 128 rows x 2 triples x 3 u32 = 3 KB (sA dead)
    u32* colbuf = rowbuf + 128 * 6;         // 3 KB
    int t = (blockIdx.x & 7) * (NDIST / 8) + (blockIdx.x >> 3);   // XCD-contiguous tiles
    int it = 0;
    while (t >= 64 - it) { t -= 64 - it; ++it; }
    int jt = it + t;
    bool diag = (jt == it);
    int wi = wave >> 1, wj = wave & 1;
    int ibase = it * 128, jbase = jt * 128;

    f32x4 acc[4][4];
    #pragma unroll
    for (int mt = 0; mt < 4; ++mt)
        #pragma unroll
        for (int nt = 0; nt < 4; ++nt)
            acc[mt][nt] = (f32x4){0.f, 0.f, 0.f, 0.f};

    const unsigned short* gsrc[8];
    short* ldst[8];
    {
        const unsigned short* comp[2] = {pa, pb};
        #pragma unroll
        for (int c = 0; c < 2; ++c)
            #pragma unroll
            for (int ch = 0; ch < 2; ++ch) {
                int r0 = (wave * 2 + ch) * 16;
                int n = (c * 2 + ch) * 2;
                gsrc[n + 0] = comp[c] + (size_t)(ibase + r0 + srow) * CH + skq;
                ldst[n + 0] = &sA[c][r0 * 32];
                gsrc[n + 1] = comp[c] + (size_t)(jbase + r0 + srow) * CH + skq;
                ldst[n + 1] = &sB[c][r0 * 32];
            }
    }

    for (int kk = 0; kk < CH; kk += 32) {
        #pragma unroll
        for (int t2 = 0; t2 < 8; ++t2) { gl_lds16(gsrc[t2], ldst[t2]); gsrc[t2] += 32; }
        __syncthreads();

        s16x8 aH[4], bH[4], aM[4], bM[4];
        #pragma unroll
        for (int mt = 0; mt < 4; ++mt)
            aH[mt] = *(const s16x8*)&sA[0][(wi * 64 + mt * 16 + lc) * 32 + cq];
        #pragma unroll
        for (int nt = 0; nt < 4; ++nt)
            bH[nt] = *(const s16x8*)&sB[0][(wj * 64 + nt * 16 + lc) * 32 + cq];
        #pragma unroll
        for (int mt = 0; mt < 4; ++mt)
            #pragma unroll
            for (int nt = 0; nt < 4; ++nt)
                acc[mt][nt] = mfma_h(aH[mt], bH[nt], acc[mt][nt]);

        #pragma unroll
        for (int nt = 0; nt < 4; ++nt)
            bM[nt] = *(const s16x8*)&sB[1][(wj * 64 + nt * 16 + lc) * 32 + cq];
        #pragma unroll
        for (int mt = 0; mt < 4; ++mt)
            #pragma unroll
            for (int nt = 0; nt < 4; ++nt)
                acc[mt][nt] = mfma_h(aH[mt], bM[nt], acc[mt][nt]);

        #pragma unroll
        for (int mt = 0; mt < 4; ++mt)
            aM[mt] = *(const s16x8*)&sA[1][(wi * 64 + mt * 16 + lc) * 32 + cq];
        #pragma unroll
        for (int mt = 0; mt < 4; ++mt)
            #pragma unroll
            for (int nt = 0; nt < 4; ++nt)
                acc[mt][nt] = mfma_h(aM[mt], bH[nt], acc[mt][nt]);

        __syncthreads();
    }

    // ---- epilogue: D' = (sq'_i + sq'_j) - 2*dot'  (uniformly 2^30-scaled -> same order)
    //      all selection on 32-bit packed (key & 0xFFFFFF80) | local_idx ----
    float sqjv[4];
    u32 lcol[4];
    #pragma unroll
    for (int nt = 0; nt < 4; ++nt) {
        sqjv[nt] = sq[jbase + wj * 64 + nt * 16 + lc];
        lcol[nt] = (u32)(wj * 64 + nt * 16 + lc);           // local col 0..127
    }
    float sqiv[4][4];
    #pragma unroll
    for (int mt = 0; mt < 4; ++mt)
        #pragma unroll
        for (int rg = 0; rg < 4; ++rg)
            sqiv[mt][rg] = sq[ibase + wi * 64 + mt * 16 + q * 4 + rg];

    // row-wise: per-row in-lane top3 + lc-butterfly; both wj waves deposit to rowbuf
    #pragma unroll
    for (int mt = 0; mt < 4; ++mt) {
        #pragma unroll
        for (int rg = 0; rg < 4; ++rg) {
            float sqi = sqiv[mt][rg];
            u32 t0 = ~0u, t1 = ~0u, t2 = ~0u;
            #pragma unroll
            for (int nt = 0; nt < 4; ++nt) {
                float dv = fmaf(acc[mt][nt][rg], -2.0f, sqi + sqjv[nt]);
                ins3u(t0, t1, t2, packdi32(dv, lcol[nt]));
            }
            #pragma unroll
            for (int m = 1; m < 16; m <<= 1) {
                u32 b0 = __shfl_xor(t0, m, 64);
                u32 b1 = __shfl_xor(t1, m, 64);
                u32 b2 = __shfl_xor(t2, m, 64);
                merge3u(t0, t1, t2, b0, b1, b2);
            }
            if (lc == 0) {
                int r = wi * 64 + mt * 16 + q * 4 + rg;
                u32* rb = &rowbuf[r * 6 + wj * 3];
                rb[0] = t0; rb[1] = t1; rb[2] = t2;
            }
        }
    }

    // col-wise (off-diag only): both wi waves deposit to colbuf
    if (!diag) {
        u32 ct[4][3];
        #pragma unroll
        for (int nt = 0; nt < 4; ++nt) { ct[nt][0] = ~0u; ct[nt][1] = ~0u; ct[nt][2] = ~0u; }
        #pragma unroll
        for (int mt = 0; mt < 4; ++mt)
            #pragma unroll
            for (int rg = 0; rg < 4; ++rg) {
                float sqi = sqiv[mt][rg];
                u32 lrow = (u32)(wi * 64 + mt * 16 + q * 4 + rg);   // local row 0..127
                #pragma unroll
                for (int nt = 0; nt < 4; ++nt) {
                    float dv = fmaf(acc[mt][nt][rg], -2.0f, sqi + sqjv[nt]);
                    ins3u(ct[nt][0], ct[nt][1], ct[nt][2], packdi32(dv, lrow));
                }
            }
        #pragma unroll
        for (int nt = 0; nt < 4; ++nt) {
            #pragma unroll
            for (int m = 16; m < 64; m <<= 1) {
                u32 b0 = __shfl_xor(ct[nt][0], m, 64);
                u32 b1 = __shfl_xor(ct[nt][1], m, 64);
                u32 b2 = __shfl_xor(ct[nt][2], m, 64);
                merge3u(ct[nt][0], ct[nt][1], ct[nt][2], b0, b1, b2);
            }
        }
        if (q == 0) {
            #pragma unroll
            for (int nt = 0; nt < 4; ++nt) {
                int col = wj * 64 + nt * 16 + lc;
                u32* cb = &colbuf[col * 6 + wi * 3];
                cb[0] = ct[nt][0]; cb[1] = ct[nt][1]; cb[2] = ct[nt][2];
            }
        }
    }

    __syncthreads();   // the ONLY epilogue barrier

    // distributed tail: threads 0..127 -> rows; 128..255 -> cols; store u32 triples
    // slot position encodes the 128-row band -> merge kernel reconstructs global idx.
    if (tid < 128) {
        u32* rb = &rowbuf[tid * 6];
        u32 t0 = rb[0], t1 = rb[1], t2 = rb[2];
        merge3u(t0, t1, t2, rb[3], rb[4], rb[5]);
        u32* dp = part + ((size_t)(ibase + tid) * 64 + jt) * 3;
        dp[0] = t0; dp[1] = t1; dp[2] = t2;
    } else if (!diag) {
        int c = tid - 128;
        u32* cb = &colbuf[c * 6];
        u32 t0 = cb[0], t1 = cb[1], t2 = cb[2];
        merge3u(t0, t1, t2, cb[3], cb[4], cb[5]);
        u32* dp = part + ((size_t)(jbase + c) * 64 + it) * 3;
        dp[0] = t0; dp[1] = t1; dp[2] = t2;
    }
}

// -- fused second stage + linear2, RETILED 32x64 (R11->R12): grid 1024 blocks (was 512
//    = 2/CU grid-starved). LDS 24 KB x dbuf = 48 KB -> 3 blocks/CU; acc 8 VGPR/wave.
//    Wave map: wave&1 = row-half (16 rows), wave>>1 = col-half (32 cols, 2 nt frags).
//    Stage: 24 (stream,chunk) items, 6 per wave. Same 6 products, same arithmetic. --
__global__ __launch_bounds__(256, 3) void gemm2_mfma(
    const unsigned short* __restrict__ Gh, const unsigned short* __restrict__ Gm,
    const unsigned short* __restrict__ Hh, const unsigned short* __restrict__ Hm,
    const unsigned short* __restrict__ Rh, const unsigned short* __restrict__ Rm,
    const unsigned short* __restrict__ Th, const unsigned short* __restrict__ Tm,
    const float* __restrict__ brel, float* __restrict__ x1,
    const float* __restrict__ W2, const float* __restrict__ b2,
    float* __restrict__ out)
{
    // per buf: A streams 0..3 (32 rows): off s*1024; B streams 4..7 (64 rows): 4096+(s-4)*2048
    __shared__ short smem[2 * 12288];      // 48 KB
    int tid = threadIdx.x;
    int wave = tid >> 6, lane = tid & 63;
    int lc = lane & 15, q = lane >> 4;
    int mbase = blockIdx.x * 32, nbase = blockIdx.y * 64;

    f32x4 acc[2];
    acc[0] = (f32x4){0.f, 0.f, 0.f, 0.f};
    acc[1] = (f32x4){0.f, 0.f, 0.f, 0.f};

    int srow = lane >> 2;
    int skq  = ((lane & 3) ^ ((lane >> 3) & 3)) * 8;
    int cq   = (q ^ ((lc >> 1) & 3)) * 8;

    // ---- build this wave's 6 stage items ----
    const unsigned short* gsrc[6];
    int lofs[6];
    #pragma unroll
    for (int j = 0; j < 6; ++j) {
        int idx = wave * 6 + j;            // 0..23
        int s, c, rowb;
        if (idx < 8) { s = idx >> 1; c = idx & 1; rowb = mbase; }
        else { int k = idx - 8; s = 4 + (k >> 2); c = k & 3; rowb = nbase; }
        const unsigned short* sp =
            (s == 0) ? Gh : (s == 1) ? Gm : (s == 2) ? Hh : (s == 3) ? Hm :
            (s == 4) ? Rh : (s == 5) ? Rm : (s == 6) ? Th : Tm;
        gsrc[j] = sp + (size_t)(rowb + c * 16 + srow) * CH + skq;
        lofs[j] = (s < 4 ? s * 1024 : 4096 + (s - 4) * 2048) + c * 16 * 32;
    }

    int rh = (wave & 1) * 16;              // row-half within 32-row tile
    int cb2 = (wave >> 1) * 32;            // col-half within 64-col tile

    auto STAGE_G = [&](int bf) {
        #pragma unroll
        for (int j = 0; j < 6; ++j) { gl_lds16(gsrc[j], &smem[bf * 12288 + lofs[j]]); gsrc[j] += 32; }
    };
    auto COMPUTE_G = [&](int bf) {
        int bo = bf * 12288;
        int ar = (rh + lc) * 32 + cq;
        s16x8 gH = *(const s16x8*)&smem[bo + 0 * 1024 + ar];
        s16x8 gM = *(const s16x8*)&smem[bo + 1 * 1024 + ar];
        s16x8 hH = *(const s16x8*)&smem[bo + 2 * 1024 + ar];
        s16x8 hM = *(const s16x8*)&smem[bo + 3 * 1024 + ar];
        s16x8 rH[2], rM[2], tH[2], tM[2];
        #pragma unroll
        for (int nt = 0; nt < 2; ++nt) {
            int br = (cb2 + nt * 16 + lc) * 32 + cq;
            rH[nt] = *(const s16x8*)&smem[bo + 4096 + 0 * 2048 + br];
            rM[nt] = *(const s16x8*)&smem[bo + 4096 + 1 * 2048 + br];
            tH[nt] = *(const s16x8*)&smem[bo + 4096 + 2 * 2048 + br];
            tM[nt] = *(const s16x8*)&smem[bo + 4096 + 3 * 2048 + br];
        }
        #pragma unroll
        for (int nt = 0; nt < 2; ++nt) {
            acc[nt] = mfma_h(gH, rH[nt], acc[nt]);
            acc[nt] = mfma_h(gH, rM[nt], acc[nt]);
            acc[nt] = mfma_h(gM, rH[nt], acc[nt]);
            acc[nt] = mfma_h(hH, tH[nt], acc[nt]);
            acc[nt] = mfma_h(hH, tM[nt], acc[nt]);
            acc[nt] = mfma_h(hM, tH[nt], acc[nt]);
        }
    };

    STAGE_G(0);
    __syncthreads();
    #pragma unroll
    for (int t = 0; t < 7; ++t) {
        STAGE_G((t + 1) & 1);
        COMPUTE_G(t & 1);
        __syncthreads();
    }
    COMPUTE_G(1);

    float w20[2], w21[2];
    #pragma unroll
    for (int nt = 0; nt < 2; ++nt) {
        int col = nbase + cb2 + nt * 16 + lc;
        w20[nt] = W2[col];
        w21[nt] = W2[CH + col];
    }
    float s0[4] = {0.f, 0.f, 0.f, 0.f}, s1[4] = {0.f, 0.f, 0.f, 0.f};
    #pragma unroll
    for (int nt = 0; nt < 2; ++nt) {
        int col = nbase + cb2 + nt * 16 + lc;
        float bv = brel[col];
        #pragma unroll
        for (int rg = 0; rg < 4; ++rg) {
            int row = mbase + rh + q * 4 + rg;
            float v = fmaxf(fmaf(acc[nt][rg], ACC_UNSCL, bv), 0.0f);
            x1[(size_t)row * CH + col] = v;
            s0[rg] = fmaf(v, w20[nt], s0[rg]);
            s1[rg] = fmaf(v, w21[nt], s1[rg]);
        }
    }
    #pragma unroll
    for (int rg = 0; rg < 4; ++rg) {
        #pragma unroll
        for (int m = 1; m < 16; m <<= 1) {
            s0[rg] += __shfl_xor(s0[rg], m, 64);
            s1[rg] += __shfl_xor(s1[rg], m, 64);
        }
    }
    if (lc == 0) {
        #pragma unroll
        for (int rg = 0; rg < 4; ++rg) {
            int row = mbase + rh + q * 4 + rg;
            float o0 = s0[rg], o1 = s1[rg];
            if (nbase == 0 && (wave >> 1) == 0) { o0 += b2[0]; o1 += b2[1]; }  // once per row
            atomicAdd(&out[(size_t)row * 2 + 0], o0);
            atomicAdd(&out[(size_t)row * 2 + 1], o1);
        }
    }
}

// ---- merge 64 partial top-3s per row (u32 slots -> u64 with global idx), gather the
//      3 neighbor rows from the h SPLITS (h = (hh+hm), already *HSCL), emit agg splits ----
__global__ __launch_bounds__(256) void merge_gather_split(
    const u32* __restrict__ part,
    const unsigned short* __restrict__ hh, const unsigned short* __restrict__ hm,
    unsigned short* __restrict__ gh, unsigned short* __restrict__ gm)
{
    int wave = threadIdx.x >> 6, lane = threadIdx.x & 63;
    int row = blockIdx.x * 4 + wave;
    const u32* pr = part + (size_t)row * 192 + lane * 3;
    u32 a0 = pr[0], a1 = pr[1], a2 = pr[2];
    int gb = lane * 128;                       // slot == 128-row band
    u64 t0 = ((u64)(a0 & 0xFFFFFF80u) << 32) | (u32)(gb + (int)(a0 & 127u));
    u64 t1 = ((u64)(a1 & 0xFFFFFF80u) << 32) | (u32)(gb + (int)(a1 & 127u));
    u64 t2 = ((u64)(a2 & 0xFFFFFF80u) << 32) | (u32)(gb + (int)(a2 & 127u));
    #pragma unroll
    for (int m = 32; m; m >>= 1) {
        u64 b0 = __shfl_xor(t0, m, 64);
        u64 b1 = __shfl_xor(t1, m, 64);
        u64 b2 = __shfl_xor(t2, m, 64);
        merge3(t0, t1, t2, b0, b1, b2);
    }
    int i0 = (int)(t0 & 0xffffffffu);
    int i1 = (int)(t1 & 0xffffffffu);
    int i2 = (int)(t2 & 0xffffffffu);
    int c4 = lane * 4;
    ushort4 ah = *(const ushort4*)(hh + (size_t)i0 * CH + c4);
    ushort4 am = *(const ushort4*)(hm + (size_t)i0 * CH + c4);
    ushort4 bh = *(const ushort4*)(hh + (size_t)i1 * CH + c4);
    ushort4 bm = *(const ushort4*)(hm + (size_t)i1 * CH + c4);
    ushort4 ch = *(const ushort4*)(hh + (size_t)i2 * CH + c4);
    ushort4 cm = *(const ushort4*)(hm + (size_t)i2 * CH + c4);
    float ox = (h2f(ah.x) + h2f(am.x)) + (h2f(bh.x) + h2f(bm.x)) + (h2f(ch.x) + h2f(cm.x));
    float oy = (h2f(ah.y) + h2f(am.y)) + (h2f(bh.y) + h2f(bm.y)) + (h2f(ch.y) + h2f(cm.y));
    float oz = (h2f(ah.z) + h2f(am.z)) + (h2f(bh.z) + h2f(bm.z)) + (h2f(ch.z) + h2f(cm.z));
    float ow = (h2f(ah.w) + h2f(am.w)) + (h2f(bh.w) + h2f(bm.w)) + (h2f(ch.w) + h2f(cm.w));
    ushort4 H, M;
    split2h(ox, H.x, M.x);     // already *HSCL scale
    split2h(oy, H.y, M.y);
    split2h(oz, H.z, M.z);
    split2h(ow, H.w, M.w);
    int i = row * CH + lane * 4;
    *(ushort4*)(gh + i) = H;
    *(ushort4*)(gm + i) = M;
}

extern "C" void kernel_launch(void* const* d_in, const int* in_sizes, int n_in,
                              void* d_out, int out_size, void* d_ws, size_t ws_size,
                              hipStream_t stream) {
    const float* x    = (const float*)d_in[0];
    const float* W1   = (const float*)d_in[1];
    const float* b1   = (const float*)d_in[2];
    const float* Wrel = (const float*)d_in[3];
    const float* brel = (const float*)d_in[4];
    const float* Wroot= (const float*)d_in[5];
    const float* W2   = (const float*)d_in[6];
    const float* b2   = (const float*)d_in[7];

    float* outp = (float*)d_out;            // [8192*2] first
    float* x1   = outp + (size_t)NN * 2;    // [8192*256] second output

    char* ws = (char*)d_ws;
    float* sq = (float*)ws;                                          // 32 KB (pad to 64K)
    char* base = ws + (64ull << 10);
    unsigned short* pa = (unsigned short*)(base);                    // 4 MB (f16 H of p*2^15)
    unsigned short* pb = (unsigned short*)(base + (4ull  << 20));    // 4 MB (f16 M)
    u32* part          = (u32*)          (base + (12ull << 20));     // 6.3 MB (8192*64*3*4)
    char* base2 = base + (12ull << 20) + (13ull << 20);
    unsigned short* hh = (unsigned short*)(base2);                   // 4 MB
    unsigned short* hm = (unsigned short*)(base2 + (4ull  << 20));   // 4 MB
    unsigned short* xh = (unsigned short*)(base2 + (8ull  << 20));   // 4 MB (reused as gh)
    unsigned short* xm = (unsigned short*)(base2 + (12ull << 20));   // 4 MB (reused as gm)
    char* wsp = base2 + (16ull << 20);
    unsigned short* W1h   = (unsigned short*)(wsp);
    unsigned short* W1m   = (unsigned short*)(wsp + 131072);
    unsigned short* Wrelh = (unsigned short*)(wsp + 2 * 131072);
    unsigned short* Wrelm = (unsigned short*)(wsp + 3 * 131072);
    unsigned short* Wrth  = (unsigned short*)(wsp + 4 * 131072);
    unsigned short* Wrtm  = (unsigned short*)(wsp + 5 * 131072);
    unsigned short* gh = xh;               // x splits dead after gemm_h branch
    unsigned short* gm = xm;

    // 1. fused: softmax -> sq + p splits + x splits + outp zeroing, and weight splits
    softmax_split_kernel<<<NN / 4 + 192, 256, 0, stream>>>(
        x, sq, pa, pb, xh, xm, outp,
        W1, Wrel, Wroot, W1h, W1m, Wrelh, Wrelm, Wrth, Wrtm);
    // 2. FUSED: dist tiles (2080, XCD-swizzled dynamic dispatch) + gemm_h backfill (512)
    dist_gemmh_fused<<<NDIST + 512, 256, 0, stream>>>(
        pa, pb, sq, part,
        xh, xm, W1h, W1m, b1, hh, hm);
    // 3. global top3 merge + gather-sum of h-row splits, fused split of agg
    merge_gather_split<<<NN / 4, 256, 0, stream>>>(part, hh, hm, gh, gm);
    // 4. x1 = relu(agg @ Wrel^T + brel + h @ Wroot^T); out += x1-tile @ W2^T (+b2)
    //    32x64 tiles: 1024 blocks, 3/CU (was 512 @ 2/CU grid-starved)
    gemm2_mfma<<<dim3(NN / 32, CH / 64), 256, 0, stream>>>(
        gh, gm, hh, hm, Wrelh, Wrelm, Wrth, Wrtm, brel, x1, W2, b2, outp);
}

// Round 13
// 173.737 us; speedup vs baseline: 1.0543x; 1.0543x over previous
//
#include <hip/hip_runtime.h>
#include <hip/hip_fp16.h>
#include <math.h>

#define NN 8192
#define CH 256
#define NDIST 2080

// ---- ordering/affine-invariant scaling so all f16 split residuals are normal-range ----
// dist operands: p * 2^15 (pure positive scaling -> distance ORDER unchanged; sq * 2^30)
// gemm operands: x,h,agg * 2^4 ; weights * 2^6 ; epilogue un-scales acc by 2^-10
#define PSCL      32768.0f
#define SQSCL     1073741824.0f     // (2^15)^2
#define XSCL      16.0f
#define WSCL      64.0f
#define HSCL      16.0f
#define ACC_UNSCL 0.0009765625f     // 2^-10

typedef unsigned long long u64;
typedef unsigned u32;
typedef __attribute__((ext_vector_type(8))) short s16x8;
typedef __attribute__((ext_vector_type(8))) _Float16 f16x8;
typedef __attribute__((ext_vector_type(4))) float f32x4;

__device__ __forceinline__ f32x4 mfma_h(s16x8 a, s16x8 b, f32x4 c) {
    return __builtin_amdgcn_mfma_f32_16x16x32_f16(
        __builtin_bit_cast(f16x8, a), __builtin_bit_cast(f16x8, b), c, 0, 0, 0);
}

__device__ __forceinline__ u64 umin64(u64 a, u64 b) { return a < b ? a : b; }
__device__ __forceinline__ u64 umax64(u64 a, u64 b) { return a < b ? b : a; }

__device__ __forceinline__ void merge3(u64 &a0, u64 &a1, u64 &a2, u64 b0, u64 b1, u64 b2) {
    u64 m0 = umin64(a0, b0), M0 = umax64(a0, b0);
    u64 m1 = umin64(a1, b1);
    u64 m2 = umin64(a2, b2);
    u64 s  = umin64(M0, m1), S = umax64(M0, m1);
    a0 = m0;
    a1 = s;
    a2 = umin64(S, m2);
}

// ---- 32-bit packed (truncated-dist-key | 7-bit local index) top-3 primitives ----
// key = (ieee_bits(max(d,0)) & 0xFFFFFF80) | local_idx. d>=0 -> bits monotone unsigned.
__device__ __forceinline__ u32 umin32(u32 a, u32 b) { return a < b ? a : b; }
__device__ __forceinline__ u32 umax32(u32 a, u32 b) { return a < b ? b : a; }

__device__ __forceinline__ void ins3u(u32 &t0, u32 &t1, u32 &t2, u32 v) {
    u32 lo0 = umin32(t0, v), hi0 = umax32(t0, v);
    t0 = lo0;
    u32 lo1 = umin32(t1, hi0), hi1 = umax32(t1, hi0);
    t1 = lo1;
    t2 = umin32(t2, hi1);
}

__device__ __forceinline__ void merge3u(u32 &a0, u32 &a1, u32 &a2, u32 b0, u32 b1, u32 b2) {
    u32 m0 = umin32(a0, b0), M0 = umax32(a0, b0);
    u32 m1 = umin32(a1, b1);
    u32 m2 = umin32(a2, b2);
    u32 s  = umin32(M0, m1), S = umax32(M0, m1);
    a0 = m0;
    a1 = s;
    a2 = umin32(S, m2);
}

__device__ __forceinline__ u32 packdi32(float d, u32 lidx) {
    return (__float_as_uint(fmaxf(d, 0.0f)) & 0xFFFFFF80u) | lidx;
}

__device__ __forceinline__ void gl_lds16(const void* g, void* l) {
    __builtin_amdgcn_global_load_lds(
        (const __attribute__((address_space(1))) unsigned int*)g,
        (__attribute__((address_space(3))) unsigned int*)l, 16, 0, 0);
}

// ---------------- f16 2-way split (H = f16(a), M = f16(a - H)) ----------------
__device__ __forceinline__ void split2h(float a, unsigned short& h, unsigned short& m) {
    __half bh = __float2half(a);
    float r = a - __half2float(bh);
    __half bm = __float2half(r);
    h = __half_as_ushort(bh);
    m = __half_as_ushort(bm);
}

__device__ __forceinline__ float h2f(unsigned short u) {
    return __half2float(__ushort_as_half(u));
}

// ------- fused: softmax + sq + f16-split(p*2^15) + f16-split(x*2^4) + outp zeroing
//         PLUS weight f16 splits (W * 2^6) ---
__global__ __launch_bounds__(256) void softmax_split_kernel(
    const float* __restrict__ x, float* __restrict__ sq,
    unsigned short* __restrict__ pa, unsigned short* __restrict__ pb,
    unsigned short* __restrict__ xh, unsigned short* __restrict__ xm,
    float* __restrict__ outp,
    const float* __restrict__ W1, const float* __restrict__ Wrel, const float* __restrict__ Wroot,
    unsigned short* __restrict__ d0h, unsigned short* __restrict__ d0m,
    unsigned short* __restrict__ d1h, unsigned short* __restrict__ d1m,
    unsigned short* __restrict__ d2h, unsigned short* __restrict__ d2m)
{
    if (blockIdx.x >= NN / 4) {
        int wb = blockIdx.x - NN / 4;      // 0..191
        int which = wb >> 6;
        const float* s = (which == 0) ? W1 : (which == 1) ? Wrel : Wroot;
        unsigned short* dh = (which == 0) ? d0h : (which == 1) ? d1h : d2h;
        unsigned short* dm = (which == 0) ? d0m : (which == 1) ? d1m : d2m;
        int i = (wb & 63) * 1024 + threadIdx.x * 4;
        float4 v = *(const float4*)(s + i);
        ushort4 H, M;
        split2h(v.x * WSCL, H.x, M.x);
        split2h(v.y * WSCL, H.y, M.y);
        split2h(v.z * WSCL, H.z, M.z);
        split2h(v.w * WSCL, H.w, M.w);
        *(ushort4*)(dh + i) = H;
        *(ushort4*)(dm + i) = M;
        return;
    }
    int wave = threadIdx.x >> 6, lane = threadIdx.x & 63;
    int row = blockIdx.x * 4 + wave;
    if (lane == 1) {    // zero the linear2 accumulators for this row (gemm2 is atomic)
        outp[row * 2 + 0] = 0.0f;
        outp[row * 2 + 1] = 0.0f;
    }
    const float4* xr = (const float4*)(x + (size_t)row * CH);
    float4 v = xr[lane];
    int i = row * CH + lane * 4;
    ushort4 XH, XM;
    split2h(v.x * XSCL, XH.x, XM.x);
    split2h(v.y * XSCL, XH.y, XM.y);
    split2h(v.z * XSCL, XH.z, XM.z);
    split2h(v.w * XSCL, XH.w, XM.w);
    *(ushort4*)(xh + i) = XH;
    *(ushort4*)(xm + i) = XM;
    float m = fmaxf(fmaxf(v.x, v.y), fmaxf(v.z, v.w));
    #pragma unroll
    for (int off = 32; off; off >>= 1) m = fmaxf(m, __shfl_xor(m, off, 64));
    // p feeds ONLY neighbor selection (and sq) -> fast exp / single divide are safe
    float e0 = __expf(v.x - m), e1 = __expf(v.y - m), e2 = __expf(v.z - m), e3 = __expf(v.w - m);
    float s = (e0 + e1) + (e2 + e3);
    #pragma unroll
    for (int off = 32; off; off >>= 1) s += __shfl_xor(s, off, 64);
    float rs = 1.0f / s;
    float p0 = e0 * rs, p1 = e1 * rs, p2 = e2 * rs, p3 = e3 * rs;
    float qv = (p0 * p0 + p1 * p1) + (p2 * p2 + p3 * p3);
    #pragma unroll
    for (int off = 32; off; off >>= 1) qv += __shfl_xor(qv, off, 64);
    if (lane == 0) sq[row] = qv * SQSCL;        // scaled to match 2^30-scaled dot
    ushort4 H, M;
    split2h(p0 * PSCL, H.x, M.x);
    split2h(p1 * PSCL, H.y, M.y);
    split2h(p2 * PSCL, H.z, M.z);
    split2h(p3 * PSCL, H.w, M.w);
    *(ushort4*)(pa + i) = H;
    *(ushort4*)(pb + i) = M;
}

// ===== FUSED dispatch: blocks [0,2080) = symmetric dist tiles; [2080, 2592) = gemm_h =====
// dist: 128x128 triangular tile, 4 waves (2x2), f16 2-split, 3 products (HH, HM, MH).
// SINGLE-buffer 32 KB LDS, 2 barriers per K-step (R3/R4: beats dbuf at this grid depth).
// __launch_bounds__(256,4) — DO NOT RAISE: (256,5) forced VGPR 48 < the 64-reg
// accumulator -> scratch spills -> FETCH/WRITE x3, dur x2.4 (R6 post-mortem).
// NO setprio (R5: -83%). NO cooperative mega-fusion (R9 race / R10 harness failure).
// gemm2 stays 64x64 (R12: 32x64 retile doubled B-panel staging -> +5.5 us).
// Top-3 epilogue on 32-bit packed keys; part stored as u32x3 (band id encoded by slot).
__global__ __launch_bounds__(256, 4) void dist_gemmh_fused(
    const unsigned short* __restrict__ pa, const unsigned short* __restrict__ pb,
    const float* __restrict__ sq,
    u32* __restrict__ part,
    const unsigned short* __restrict__ Ah, const unsigned short* __restrict__ Am,
    const unsigned short* __restrict__ Wh, const unsigned short* __restrict__ Wm,
    const float* __restrict__ bias,
    unsigned short* __restrict__ oh, unsigned short* __restrict__ om)
{
    __shared__ short sA[2][128 * 32];   // [comp][...] 16 KB
    __shared__ short sB[2][128 * 32];   // 16 KB

    int tid = threadIdx.x;
    int wave = tid >> 6, lane = tid & 63;
    int lc = lane & 15, q = lane >> 4;
    int srow = lane >> 2;
    int skq  = ((lane & 3) ^ ((lane >> 3) & 3)) * 8;   // XOR-swizzled global 16B slot
    int cq   = (q ^ ((lc >> 1) & 3)) * 8;              // swizzled LDS slot for frag reads

    if (blockIdx.x >= NDIST) {
        // ---------------- gemm_h branch ----------------
        int b = blockIdx.x - NDIST;                    // 0..511
        int mbase = (b & 127) * 64, nbase = (b >> 7) * 64;
        short* sAh = &sA[0][0];
        short* sAm = &sA[0][64 * 32];
        short* sBh = &sA[1][0];
        short* sBm = &sA[1][64 * 32];

        f32x4 acc[4];
        #pragma unroll
        for (int nt = 0; nt < 4; ++nt) acc[nt] = (f32x4){0.f, 0.f, 0.f, 0.f};

        int r0 = wave * 16;
        const unsigned short* gsrc[4];
        short* ldst[4];
        gsrc[0] = Ah + (size_t)(mbase + r0 + srow) * CH + skq;  ldst[0] = &sAh[r0 * 32];
        gsrc[1] = Am + (size_t)(mbase + r0 + srow) * CH + skq;  ldst[1] = &sAm[r0 * 32];
        gsrc[2] = Wh + (size_t)(nbase + r0 + srow) * CH + skq;  ldst[2] = &sBh[r0 * 32];
        gsrc[3] = Wm + (size_t)(nbase + r0 + srow) * CH + skq;  ldst[3] = &sBm[r0 * 32];

        for (int kk = 0; kk < CH; kk += 32) {
            #pragma unroll
            for (int t = 0; t < 4; ++t) { gl_lds16(gsrc[t], ldst[t]); gsrc[t] += 32; }
            __syncthreads();
            s16x8 aH, aM, bH[4], bM[4];
            aH = *(const s16x8*)&sAh[(wave * 16 + lc) * 32 + cq];
            aM = *(const s16x8*)&sAm[(wave * 16 + lc) * 32 + cq];
            #pragma unroll
            for (int nt = 0; nt < 4; ++nt) {
                bH[nt] = *(const s16x8*)&sBh[(nt * 16 + lc) * 32 + cq];
                bM[nt] = *(const s16x8*)&sBm[(nt * 16 + lc) * 32 + cq];
            }
            #pragma unroll
            for (int nt = 0; nt < 4; ++nt)
                acc[nt] = mfma_h(aH, bH[nt], acc[nt]);
            #pragma unroll
            for (int nt = 0; nt < 4; ++nt)
                acc[nt] = mfma_h(aH, bM[nt], acc[nt]);
            #pragma unroll
            for (int nt = 0; nt < 4; ++nt)
                acc[nt] = mfma_h(aM, bH[nt], acc[nt]);
            __syncthreads();
        }

        #pragma unroll
        for (int nt = 0; nt < 4; ++nt) {
            float bv = bias[nbase + nt * 16 + lc];
            #pragma unroll
            for (int rg = 0; rg < 4; ++rg) {
                int row = mbase + wave * 16 + q * 4 + rg;
                int col = nbase + nt * 16 + lc;
                float v = fmaxf(fmaf(acc[nt][rg], ACC_UNSCL, bv), 0.0f);
                unsigned short hh_, hm_;
                split2h(v * HSCL, hh_, hm_);
                oh[(size_t)row * CH + col] = hh_;
                om[(size_t)row * CH + col] = hm_;
            }
        }
        return;
    }

    // ---------------- dist branch (XCD-swizzled compact triangular id) ----------------
    u32* rowbuf = (u32*)&sA[0][0];          // 128 rows x 2 triples x 3 u32 = 3 KB (sA dead)
    u32* colbuf = rowbuf + 128 * 6;         // 3 KB
    int t = (blockIdx.x & 7) * (NDIST / 8) + (blockIdx.x >> 3);   // XCD-contiguous tiles
    int it = 0;
    while (t >= 64 - it) { t -= 64 - it; ++it; }
    int jt = it + t;
    bool diag = (jt == it);
    int wi = wave >> 1, wj = wave & 1;
    int ibase = it * 128, jbase = jt * 128;

    f32x4 acc[4][4];
    #pragma unroll
    for (int mt = 0; mt < 4; ++mt)
        #pragma unroll
        for (int nt = 0; nt < 4; ++nt)
            acc[mt][nt] = (f32x4){0.f, 0.f, 0.f, 0.f};

    const unsigned short* gsrc[8];
    short* ldst[8];
    {
        const unsigned short* comp[2] = {pa, pb};
        #pragma unroll
        for (int c = 0; c < 2; ++c)
            #pragma unroll
            for (int ch = 0; ch < 2; ++ch) {
                int r0 = (wave * 2 + ch) * 16;
                int n = (c * 2 + ch) * 2;
                gsrc[n + 0] = comp[c] + (size_t)(ibase + r0 + srow) * CH + skq;
                ldst[n + 0] = &sA[c][r0 * 32];
                gsrc[n + 1] = comp[c] + (size_t)(jbase + r0 + srow) * CH + skq;
                ldst[n + 1] = &sB[c][r0 * 32];
            }
    }

    for (int kk = 0; kk < CH; kk += 32) {
        #pragma unroll
        for (int t2 = 0; t2 < 8; ++t2) { gl_lds16(gsrc[t2], ldst[t2]); gsrc[t2] += 32; }
        __syncthreads();

        s16x8 aH[4], bH[4], aM[4], bM[4];
        #pragma unroll
        for (int mt = 0; mt < 4; ++mt)
            aH[mt] = *(const s16x8*)&sA[0][(wi * 64 + mt * 16 + lc) * 32 + cq];
        #pragma unroll
        for (int nt = 0; nt < 4; ++nt)
            bH[nt] = *(const s16x8*)&sB[0][(wj * 64 + nt * 16 + lc) * 32 + cq];
        #pragma unroll
        for (int mt = 0; mt < 4; ++mt)
            #pragma unroll
            for (int nt = 0; nt < 4; ++nt)
                acc[mt][nt] = mfma_h(aH[mt], bH[nt], acc[mt][nt]);

        #pragma unroll
        for (int nt = 0; nt < 4; ++nt)
            bM[nt] = *(const s16x8*)&sB[1][(wj * 64 + nt * 16 + lc) * 32 + cq];
        #pragma unroll
        for (int mt = 0; mt < 4; ++mt)
            #pragma unroll
            for (int nt = 0; nt < 4; ++nt)
                acc[mt][nt] = mfma_h(aH[mt], bM[nt], acc[mt][nt]);

        #pragma unroll
        for (int mt = 0; mt < 4; ++mt)
            aM[mt] = *(const s16x8*)&sA[1][(wi * 64 + mt * 16 + lc) * 32 + cq];
        #pragma unroll
        for (int mt = 0; mt < 4; ++mt)
            #pragma unroll
            for (int nt = 0; nt < 4; ++nt)
                acc[mt][nt] = mfma_h(aM[mt], bH[nt], acc[mt][nt]);

        __syncthreads();
    }

    // ---- epilogue: D' = (sq'_i + sq'_j) - 2*dot'  (uniformly 2^30-scaled -> same order)
    //      all selection on 32-bit packed (key & 0xFFFFFF80) | local_idx ----
    float sqjv[4];
    u32 lcol[4];
    #pragma unroll
    for (int nt = 0; nt < 4; ++nt) {
        sqjv[nt] = sq[jbase + wj * 64 + nt * 16 + lc];
        lcol[nt] = (u32)(wj * 64 + nt * 16 + lc);           // local col 0..127
    }
    float sqiv[4][4];
    #pragma unroll
    for (int mt = 0; mt < 4; ++mt)
        #pragma unroll
        for (int rg = 0; rg < 4; ++rg)
            sqiv[mt][rg] = sq[ibase + wi * 64 + mt * 16 + q * 4 + rg];

    // row-wise: per-row in-lane top3 + lc-butterfly; both wj waves deposit to rowbuf
    #pragma unroll
    for (int mt = 0; mt < 4; ++mt) {
        #pragma unroll
        for (int rg = 0; rg < 4; ++rg) {
            float sqi = sqiv[mt][rg];
            u32 t0 = ~0u, t1 = ~0u, t2 = ~0u;
            #pragma unroll
            for (int nt = 0; nt < 4; ++nt) {
                float dv = fmaf(acc[mt][nt][rg], -2.0f, sqi + sqjv[nt]);
                ins3u(t0, t1, t2, packdi32(dv, lcol[nt]));
            }
            #pragma unroll
            for (int m = 1; m < 16; m <<= 1) {
                u32 b0 = __shfl_xor(t0, m, 64);
                u32 b1 = __shfl_xor(t1, m, 64);
                u32 b2 = __shfl_xor(t2, m, 64);
                merge3u(t0, t1, t2, b0, b1, b2);
            }
            if (lc == 0) {
                int r = wi * 64 + mt * 16 + q * 4 + rg;
                u32* rb = &rowbuf[r * 6 + wj * 3];
                rb[0] = t0; rb[1] = t1; rb[2] = t2;
            }
        }
    }

    // col-wise (off-diag only): both wi waves deposit to colbuf
    if (!diag) {
        u32 ct[4][3];
        #pragma unroll
        for (int nt = 0; nt < 4; ++nt) { ct[nt][0] = ~0u; ct[nt][1] = ~0u; ct[nt][2] = ~0u; }
        #pragma unroll
        for (int mt = 0; mt < 4; ++mt)
            #pragma unroll
            for (int rg = 0; rg < 4; ++rg) {
                float sqi = sqiv[mt][rg];
                u32 lrow = (u32)(wi * 64 + mt * 16 + q * 4 + rg);   // local row 0..127
                #pragma unroll
                for (int nt = 0; nt < 4; ++nt) {
                    float dv = fmaf(acc[mt][nt][rg], -2.0f, sqi + sqjv[nt]);
                    ins3u(ct[nt][0], ct[nt][1], ct[nt][2], packdi32(dv, lrow));
                }
            }
        #pragma unroll
        for (int nt = 0; nt < 4; ++nt) {
            #pragma unroll
            for (int m = 16; m < 64; m <<= 1) {
                u32 b0 = __shfl_xor(ct[nt][0], m, 64);
                u32 b1 = __shfl_xor(ct[nt][1], m, 64);
                u32 b2 = __shfl_xor(ct[nt][2], m, 64);
                merge3u(ct[nt][0], ct[nt][1], ct[nt][2], b0, b1, b2);
            }
        }
        if (q == 0) {
            #pragma unroll
            for (int nt = 0; nt < 4; ++nt) {
                int col = wj * 64 + nt * 16 + lc;
                u32* cb = &colbuf[col * 6 + wi * 3];
                cb[0] = ct[nt][0]; cb[1] = ct[nt][1]; cb[2] = ct[nt][2];
            }
        }
    }

    __syncthreads();   // the ONLY epilogue barrier

    // distributed tail: threads 0..127 -> rows; 128..255 -> cols; store u32 triples
    // slot position encodes the 128-row band -> merge kernel reconstructs global idx.
    if (tid < 128) {
        u32* rb = &rowbuf[tid * 6];
        u32 t0 = rb[0], t1 = rb[1], t2 = rb[2];
        merge3u(t0, t1, t2, rb[3], rb[4], rb[5]);
        u32* dp = part + ((size_t)(ibase + tid) * 64 + jt) * 3;
        dp[0] = t0; dp[1] = t1; dp[2] = t2;
    } else if (!diag) {
        int c = tid - 128;
        u32* cb = &colbuf[c * 6];
        u32 t0 = cb[0], t1 = cb[1], t2 = cb[2];
        merge3u(t0, t1, t2, cb[3], cb[4], cb[5]);
        u32* dp = part + ((size_t)(jbase + c) * 64 + it) * 3;
        dp[0] = t0; dp[1] = t1; dp[2] = t2;
    }
}

// -- fused second stage + linear2: x1 = relu((agg'@Wrel'^T + h'@Wroot'^T)*2^-10 + brel);
//    out += partial(x1_tile @ W2^T) via atomics. 64x64 dbuf single-barrier K-loop —
//    verified optimum (R12: 32x64 retile doubled B staging, +5.5 us; R3: dbuf needed
//    here because grid is 2/CU with no backfill). --
__global__ __launch_bounds__(256, 2) void gemm2_mfma(
    const unsigned short* __restrict__ Gh, const unsigned short* __restrict__ Gm,
    const unsigned short* __restrict__ Hh, const unsigned short* __restrict__ Hm,
    const unsigned short* __restrict__ Rh, const unsigned short* __restrict__ Rm,
    const unsigned short* __restrict__ Th, const unsigned short* __restrict__ Tm,
    const float* __restrict__ brel, float* __restrict__ x1,
    const float* __restrict__ W2, const float* __restrict__ b2,
    float* __restrict__ out)
{
    __shared__ short sS[2][8][64 * 32];    // [buf][stream][...] = 64 KB
    int tid = threadIdx.x;
    int wave = tid >> 6, lane = tid & 63;
    int lc = lane & 15, q = lane >> 4;
    int mbase = blockIdx.x * 64, nbase = blockIdx.y * 64;

    f32x4 acc[4];
    #pragma unroll
    for (int nt = 0; nt < 4; ++nt) acc[nt] = (f32x4){0.f, 0.f, 0.f, 0.f};

    int srow = lane >> 2;
    int skq  = ((lane & 3) ^ ((lane >> 3) & 3)) * 8;
    int r0 = wave * 16;

    const unsigned short* gsrc[8];
    gsrc[0] = Gh + (size_t)(mbase + r0 + srow) * CH + skq;
    gsrc[1] = Gm + (size_t)(mbase + r0 + srow) * CH + skq;
    gsrc[2] = Hh + (size_t)(mbase + r0 + srow) * CH + skq;
    gsrc[3] = Hm + (size_t)(mbase + r0 + srow) * CH + skq;
    gsrc[4] = Rh + (size_t)(nbase + r0 + srow) * CH + skq;
    gsrc[5] = Rm + (size_t)(nbase + r0 + srow) * CH + skq;
    gsrc[6] = Th + (size_t)(nbase + r0 + srow) * CH + skq;
    gsrc[7] = Tm + (size_t)(nbase + r0 + srow) * CH + skq;
    int cq = (q ^ ((lc >> 1) & 3)) * 8;

    auto STAGE_G = [&](int bf) {
        #pragma unroll
        for (int s = 0; s < 8; ++s) { gl_lds16(gsrc[s], &sS[bf][s][r0 * 32]); gsrc[s] += 32; }
    };
    auto COMPUTE_G = [&](int bf) {
        s16x8 gH, gM, hH, hM, rH[4], rM[4], tH[4], tM[4];
        int ar = (wave * 16 + lc) * 32 + cq;
        gH = *(const s16x8*)&sS[bf][0][ar];
        gM = *(const s16x8*)&sS[bf][1][ar];
        hH = *(const s16x8*)&sS[bf][2][ar];
        hM = *(const s16x8*)&sS[bf][3][ar];
        #pragma unroll
        for (int nt = 0; nt < 4; ++nt) {
            int br = (nt * 16 + lc) * 32 + cq;
            rH[nt] = *(const s16x8*)&sS[bf][4][br];
            rM[nt] = *(const s16x8*)&sS[bf][5][br];
            tH[nt] = *(const s16x8*)&sS[bf][6][br];
            tM[nt] = *(const s16x8*)&sS[bf][7][br];
        }
        #pragma unroll
        for (int nt = 0; nt < 4; ++nt) {
            acc[nt] = mfma_h(gH, rH[nt], acc[nt]);
            acc[nt] = mfma_h(gH, rM[nt], acc[nt]);
            acc[nt] = mfma_h(gM, rH[nt], acc[nt]);
            acc[nt] = mfma_h(hH, tH[nt], acc[nt]);
            acc[nt] = mfma_h(hH, tM[nt], acc[nt]);
            acc[nt] = mfma_h(hM, tH[nt], acc[nt]);
        }
    };

    STAGE_G(0);
    __syncthreads();
    #pragma unroll
    for (int t = 0; t < 7; ++t) {
        STAGE_G((t + 1) & 1);
        COMPUTE_G(t & 1);
        __syncthreads();
    }
    COMPUTE_G(1);

    float w20[4], w21[4];
    #pragma unroll
    for (int nt = 0; nt < 4; ++nt) {
        w20[nt] = W2[nbase + nt * 16 + lc];
        w21[nt] = W2[CH + nbase + nt * 16 + lc];
    }
    float s0[4] = {0.f, 0.f, 0.f, 0.f}, s1[4] = {0.f, 0.f, 0.f, 0.f};
    #pragma unroll
    for (int nt = 0; nt < 4; ++nt) {
        float bv = brel[nbase + nt * 16 + lc];
        #pragma unroll
        for (int rg = 0; rg < 4; ++rg) {
            int row = mbase + wave * 16 + q * 4 + rg;
            int col = nbase + nt * 16 + lc;
            float v = fmaxf(fmaf(acc[nt][rg], ACC_UNSCL, bv), 0.0f);
            x1[(size_t)row * CH + col] = v;
            s0[rg] = fmaf(v, w20[nt], s0[rg]);
            s1[rg] = fmaf(v, w21[nt], s1[rg]);
        }
    }
    #pragma unroll
    for (int rg = 0; rg < 4; ++rg) {
        #pragma unroll
        for (int m = 1; m < 16; m <<= 1) {
            s0[rg] += __shfl_xor(s0[rg], m, 64);
            s1[rg] += __shfl_xor(s1[rg], m, 64);
        }
    }
    if (lc == 0) {
        #pragma unroll
        for (int rg = 0; rg < 4; ++rg) {
            int row = mbase + wave * 16 + q * 4 + rg;
            float o0 = s0[rg], o1 = s1[rg];
            if (nbase == 0) { o0 += b2[0]; o1 += b2[1]; }
            atomicAdd(&out[(size_t)row * 2 + 0], o0);
            atomicAdd(&out[(size_t)row * 2 + 1], o1);
        }
    }
}

// ---- merge 64 partial top-3s per row (u32 slots -> u64 with global idx), gather the
//      3 neighbor rows from the h SPLITS (h = (hh+hm), already *HSCL), emit agg splits ----
__global__ __launch_bounds__(256) void merge_gather_split(
    const u32* __restrict__ part,
    const unsigned short* __restrict__ hh, const unsigned short* __restrict__ hm,
    unsigned short* __restrict__ gh, unsigned short* __restrict__ gm)
{
    int wave = threadIdx.x >> 6, lane = threadIdx.x & 63;
    int row = blockIdx.x * 4 + wave;
    const u32* pr = part + (size_t)row * 192 + lane * 3;
    u32 a0 = pr[0], a1 = pr[1], a2 = pr[2];
    int gb = lane * 128;                       // slot == 128-row band
    u64 t0 = ((u64)(a0 & 0xFFFFFF80u) << 32) | (u32)(gb + (int)(a0 & 127u));
    u64 t1 = ((u64)(a1 & 0xFFFFFF80u) << 32) | (u32)(gb + (int)(a1 & 127u));
    u64 t2 = ((u64)(a2 & 0xFFFFFF80u) << 32) | (u32)(gb + (int)(a2 & 127u));
    #pragma unroll
    for (int m = 32; m; m >>= 1) {
        u64 b0 = __shfl_xor(t0, m, 64);
        u64 b1 = __shfl_xor(t1, m, 64);
        u64 b2 = __shfl_xor(t2, m, 64);
        merge3(t0, t1, t2, b0, b1, b2);
    }
    int i0 = (int)(t0 & 0xffffffffu);
    int i1 = (int)(t1 & 0xffffffffu);
    int i2 = (int)(t2 & 0xffffffffu);
    int c4 = lane * 4;
    ushort4 ah = *(const ushort4*)(hh + (size_t)i0 * CH + c4);
    ushort4 am = *(const ushort4*)(hm + (size_t)i0 * CH + c4);
    ushort4 bh = *(const ushort4*)(hh + (size_t)i1 * CH + c4);
    ushort4 bm = *(const ushort4*)(hm + (size_t)i1 * CH + c4);
    ushort4 ch = *(const ushort4*)(hh + (size_t)i2 * CH + c4);
    ushort4 cm = *(const ushort4*)(hm + (size_t)i2 * CH + c4);
    float ox = (h2f(ah.x) + h2f(am.x)) + (h2f(bh.x) + h2f(bm.x)) + (h2f(ch.x) + h2f(cm.x));
    float oy = (h2f(ah.y) + h2f(am.y)) + (h2f(bh.y) + h2f(bm.y)) + (h2f(ch.y) + h2f(cm.y));
    float oz = (h2f(ah.z) + h2f(am.z)) + (h2f(bh.z) + h2f(bm.z)) + (h2f(ch.z) + h2f(cm.z));
    float ow = (h2f(ah.w) + h2f(am.w)) + (h2f(bh.w) + h2f(bm.w)) + (h2f(ch.w) + h2f(cm.w));
    ushort4 H, M;
    split2h(ox, H.x, M.x);     // already *HSCL scale
    split2h(oy, H.y, M.y);
    split2h(oz, H.z, M.z);
    split2h(ow, H.w, M.w);
    int i = row * CH + lane * 4;
    *(ushort4*)(gh + i) = H;
    *(ushort4*)(gm + i) = M;
}

extern "C" void kernel_launch(void* const* d_in, const int* in_sizes, int n_in,
                              void* d_out, int out_size, void* d_ws, size_t ws_size,
                              hipStream_t stream) {
    const float* x    = (const float*)d_in[0];
    const float* W1   = (const float*)d_in[1];
    const float* b1   = (const float*)d_in[2];
    const float* Wrel = (const float*)d_in[3];
    const float* brel = (const float*)d_in[4];
    const float* Wroot= (const float*)d_in[5];
    const float* W2   = (const float*)d_in[6];
    const float* b2   = (const float*)d_in[7];

    float* outp = (float*)d_out;            // [8192*2] first
    float* x1   = outp + (size_t)NN * 2;    // [8192*256] second output

    char* ws = (char*)d_ws;
    float* sq = (float*)ws;                                          // 32 KB (pad to 64K)
    char* base = ws + (64ull << 10);
    unsigned short* pa = (unsigned short*)(base);                    // 4 MB (f16 H of p*2^15)
    unsigned short* pb = (unsigned short*)(base + (4ull  << 20));    // 4 MB (f16 M)
    u32* part          = (u32*)          (base + (12ull << 20));     // 6.3 MB (8192*64*3*4)
    char* base2 = base + (12ull << 20) + (13ull << 20);
    unsigned short* hh = (unsigned short*)(base2);                   // 4 MB
    unsigned short* hm = (unsigned short*)(base2 + (4ull  << 20));   // 4 MB
    unsigned short* xh = (unsigned short*)(base2 + (8ull  << 20));   // 4 MB (reused as gh)
    unsigned short* xm = (unsigned short*)(base2 + (12ull << 20));   // 4 MB (reused as gm)
    char* wsp = base2 + (16ull << 20);
    unsigned short* W1h   = (unsigned short*)(wsp);
    unsigned short* W1m   = (unsigned short*)(wsp + 131072);
    unsigned short* Wrelh = (unsigned short*)(wsp + 2 * 131072);
    unsigned short* Wrelm = (unsigned short*)(wsp + 3 * 131072);
    unsigned short* Wrth  = (unsigned short*)(wsp + 4 * 131072);
    unsigned short* Wrtm  = (unsigned short*)(wsp + 5 * 131072);
    unsigned short* gh = xh;               // x splits dead after gemm_h branch
    unsigned short* gm = xm;

    // 1. fused: softmax -> sq + p splits + x splits + outp zeroing, and weight splits
    softmax_split_kernel<<<NN / 4 + 192, 256, 0, stream>>>(
        x, sq, pa, pb, xh, xm, outp,
        W1, Wrel, Wroot, W1h, W1m, Wrelh, Wrelm, Wrth, Wrtm);
    // 2. FUSED: dist tiles (2080, XCD-swizzled dynamic dispatch) + gemm_h backfill (512)
    dist_gemmh_fused<<<NDIST + 512, 256, 0, stream>>>(
        pa, pb, sq, part,
        xh, xm, W1h, W1m, b1, hh, hm);
    // 3. global top3 merge + gather-sum of h-row splits, fused split of agg
    merge_gather_split<<<NN / 4, 256, 0, stream>>>(part, hh, hm, gh, gm);
    // 4. x1 = relu(agg @ Wrel^T + brel + h @ Wroot^T); out += x1-tile @ W2^T (+b2)
    gemm2_mfma<<<dim3(NN / 64, CH / 64), 256, 0, stream>>>(
        gh, gm, hh, hm, Wrelh, Wrelm, Wrth, Wrtm, brel, x1, W2, b2, outp);
}